// Round 8
// baseline (1188.147 us; speedup 1.0000x reference)
//
#include <hip/hip_runtime.h>
#include <hip/hip_cooperative_groups.h>

namespace cg = cooperative_groups;

// FDTD rollout — SINGLE cooperative kernel, 256 steps in 16 groups of TS=16.
// 256 blocks x 512 threads; block = 32x32 output tile via 64x64 halo region.
// Thread = 8-row x 1-col register strip (lane = column, wave = 8-row band).
// Inside a group: R7 structure (DPP horizontal, register vertical, LDS only
// for inter-wave boundary rows, LDS-only barrier per step).
// Between groups: __threadfence + grid.sync(); only non-center threads
// reload cur/pv from the out planes (center 32x32 stays in registers).
// c / rr / source masks / boundary masks / addresses computed ONCE.

#define HH 512
#define WW 512
#define TILE 32
#define TS 16
#define NW 8      // waves per block
#define RPT 8     // rows per thread
#define PHC ((float)(2.0 * 3.1415926 * 100.0))

// LDS-only barrier: orders ds ops without draining vmcnt (stores in flight).
#define LDS_BARRIER() asm volatile("s_waitcnt lgkmcnt(0)\n\ts_barrier" ::: "memory")

#if __has_builtin(__builtin_amdgcn_update_dpp)
__device__ __forceinline__ float nbrL(float x) {   // value from lane-1 (left)
    int i = __builtin_bit_cast(int, x);
    i = __builtin_amdgcn_update_dpp(i, i, 0x138, 0xf, 0xf, false); // wave_shr:1
    return __builtin_bit_cast(float, i);
}
__device__ __forceinline__ float nbrR(float x) {   // value from lane+1 (right)
    int i = __builtin_bit_cast(int, x);
    i = __builtin_amdgcn_update_dpp(i, i, 0x130, 0xf, 0xf, false); // wave_shl:1
    return __builtin_bit_cast(float, i);
}
#else
__device__ __forceinline__ float nbrL(float x) { return __shfl_up(x, 1, 64); }
__device__ __forceinline__ float nbrR(float x) { return __shfl_down(x, 1, 64); }
#endif

__global__ __launch_bounds__(512)
void fdtd_coop(const float* __restrict__ in_out,
               const float* __restrict__ cmap,
               const int* __restrict__ locx,
               const int* __restrict__ locy,
               const int* __restrict__ pb,
               const int* __restrict__ pid2,
               float* __restrict__ out,
               int steps)
{
    cg::grid_group gg = cg::this_grid();
    __shared__ float sb[2][NW][2][64];   // [buf][wave][top/bottom row][col]

    const int lane = threadIdx.x & 63;
    const int w    = threadIdx.x >> 6;
    const int bx   = blockIdx.x & 15;
    const int by   = blockIdx.x >> 4;
    const int gx0  = bx * TILE - TS;
    const int gy0  = by * TILE - TS;
    const int gc   = gx0 + lane;
    const int R    = w * RPT;            // local row base

    const int lx0 = locx[0], ly0 = locy[0];
    const int lx1 = locx[1], ly1 = locy[1];
    const int lx2 = locx[2], ly2 = locy[2];
    const int Bn  = pb[0] * pid2[0];

    float cur[RPT], pv[RPT], rr[RPT], cv[RPT];
    bool  issrc[RPT];
    unsigned m0 = 0, m511 = 0;
    const bool colOK = (gc >= 0) & (gc < WW);

    // ---- one-time setup: c map, coefficients, masks, initial frames ----
    #pragma unroll
    for (int j = 0; j < RPT; ++j) {
        const int gr = gy0 + R + j;
        float c = 0.f, ce = 0.f, pp = 0.f;
        if (colOK && gr >= 0 && gr < HH) {
            const int gi = gr * WW + gc;
            c  = cmap[gi];
            ce = in_out[(size_t)(HH * WW) + gi];   // frame 1 (cur)
            pp = in_out[gi];                       // frame 0 (prev)
        }
        cur[j] = ce; pv[j] = pp; cv[j] = c;
        rr[j]  = 1.0e-8f * c * c;
        issrc[j] = (gr == lx0 && gc == ly0) || (gr == lx1 && gc == ly1) ||
                   (gr == lx2 && gc == ly2);
        if (gr == 0)      m0   |= (1u << j);
        if (gr == HH - 1) m511 |= (1u << j);
    }

    // clamped LDS slots for region-edge waves (garbage-safe halo)
    const int wup = (w == 0)      ? 0      : w - 1;
    const int sup = (w == 0)      ? 0      : 1;
    const int wdn = (w == NW - 1) ? NW - 1 : w + 1;
    const int sdn = (w == NW - 1) ? 1      : 0;

    const bool edge    = (bx == 0) | (bx == 15) | (by == 0) | (by == 15);
    const bool isC0    = (gc == 0);
    const bool isC511  = (gc == WW - 1);
    // center 32x32: these threads' cur/pv stay VALID across a whole group,
    // so they both store the output and keep their state between groups.
    const bool keep    = (w >= 2) & (w <= 5) & (lane >= 16) & (lane < 48);
    const size_t rowOff = (size_t)(gy0 + R) * WW + gc;

    for (int t0 = 0; t0 < steps; t0 += TS) {
        const int nk = (steps - t0 < TS) ? (steps - t0) : TS;

        if (t0 > 0) {
            __threadfence();          // release: make group g-1 stores visible
            gg.sync();                // grid-wide barrier (device scope)
            if (!keep) {
                // reload halo ring of cur/pv from the planes just written
                const float* cF = out + (size_t)(t0 - 1) * (size_t)(HH * WW);
                const float* pF = out + (size_t)(t0 - 2) * (size_t)(HH * WW);
                #pragma unroll
                for (int j = 0; j < RPT; ++j) {
                    const int gr = gy0 + R + j;
                    float ce = 0.f, pp = 0.f;
                    if (colOK && gr >= 0 && gr < HH) {
                        const int gi = gr * WW + gc;
                        ce = cF[gi];
                        pp = pF[gi];
                    }
                    cur[j] = ce; pv[j] = pp;
                }
            }
        }
        sb[0][w][0][lane] = cur[0];
        sb[0][w][1][lane] = cur[RPT - 1];
        __syncthreads();

        if (!edge) {
            // ------------- interior blocks: branch-free stencil ------------
            #pragma unroll 2
            for (int k = 1; k <= nk; ++k) {
                const int p = (k - 1) & 1;
                const float srcv =
                    1500.0f * __sinf(PHC * (float)(Bn + t0 + k + 1) * 1.0e-4f);
                const float upb = sb[p][wup][sup][lane];
                const float dnb = sb[p][wdn][sdn][lane];
                float nc[RPT];
                #pragma unroll
                for (int j = 0; j < RPT; ++j) {
                    const float c = cur[j];
                    const float u = (j == 0)       ? upb : cur[j - 1];
                    const float d = (j == RPT - 1) ? dnb : cur[j + 1];
                    const float l = nbrL(c);
                    const float r = nbrR(c);
                    float v = 2.f * c - pv[j] +
                              rr[j] * (((u + d) + (l + r)) - 4.f * c);
                    nc[j] = issrc[j] ? srcv : v;
                }
                sb[p ^ 1][w][0][lane] = nc[0];
                sb[p ^ 1][w][1][lane] = nc[RPT - 1];
                if (keep) {
                    float* op = out + (size_t)(t0 + k - 1) * (size_t)(HH * WW)
                                    + rowOff;
                    #pragma unroll
                    for (int j = 0; j < RPT; ++j) op[j * WW] = nc[j];
                }
                #pragma unroll
                for (int j = 0; j < RPT; ++j) { pv[j] = cur[j]; cur[j] = nc[j]; }
                LDS_BARRIER();
            }
        } else {
            // ------------- edge blocks: predicated boundary overrides ------
            #pragma unroll 2
            for (int k = 1; k <= nk; ++k) {
                const int p = (k - 1) & 1;
                const float srcv =
                    1500.0f * __sinf(PHC * (float)(Bn + t0 + k + 1) * 1.0e-4f);
                const float upb = sb[p][wup][sup][lane];
                const float dnb = sb[p][wdn][sdn][lane];
                float nc[RPT];
                #pragma unroll
                for (int j = 0; j < RPT; ++j) {
                    const float c = cur[j];
                    const float u = (j == 0)       ? upb : cur[j - 1];
                    const float d = (j == RPT - 1) ? dnb : cur[j + 1];
                    const float l = nbrL(c);
                    const float r = nbrR(c);
                    float v = 2.f * c - pv[j] +
                              rr[j] * (((u + d) + (l + r)) - 4.f * c);
                    v = issrc[j] ? srcv : v;
                    // precedence (last wins): row0 < col0 < col511 < row511
                    if ((m0 >> j) & 1u)   v = c - 1.0e-4f * cv[j] * (c - d);
                    if (isC0)             v = c - 1.0e-4f * cv[j] * (c - r);
                    if (isC511)           v = c - 1.0e-4f * cv[j] * (c - l);
                    if ((m511 >> j) & 1u) v = c - 1.0e-4f * cv[j] * (c - u);
                    nc[j] = v;
                }
                sb[p ^ 1][w][0][lane] = nc[0];
                sb[p ^ 1][w][1][lane] = nc[RPT - 1];
                if (keep) {
                    float* op = out + (size_t)(t0 + k - 1) * (size_t)(HH * WW)
                                    + rowOff;
                    #pragma unroll
                    for (int j = 0; j < RPT; ++j) op[j * WW] = nc[j];
                }
                #pragma unroll
                for (int j = 0; j < RPT; ++j) { pv[j] = cur[j]; cur[j] = nc[j]; }
                LDS_BARRIER();
            }
        }
    }
}

extern "C" void kernel_launch(void* const* d_in, const int* in_sizes, int n_in,
                              void* d_out, int out_size, void* d_ws, size_t ws_size,
                              hipStream_t stream) {
    const float* in_out = (const float*)d_in[0];   // [steps+2, 1, 512, 512]
    const float* cmap   = (const float*)d_in[1];   // [1,1,512,512]
    const int*   locx   = (const int*)d_in[2];
    const int*   locy   = (const int*)d_in[3];
    const int*   pb     = (const int*)d_in[4];     // bsize1
    const int*   pid2   = (const int*)d_in[5];     // id2
    float*       outp   = (float*)d_out;

    const int HW = HH * WW;
    int steps = out_size / HW;

    void* args[] = { (void*)&in_out, (void*)&cmap, (void*)&locx, (void*)&locy,
                     (void*)&pb, (void*)&pid2, (void*)&outp, (void*)&steps };
    hipLaunchCooperativeKernel((const void*)fdtd_coop,
                               dim3((HH / TILE) * (WW / TILE)),  // 256 blocks
                               dim3(512), args, 0, stream);
}

// Round 9
// 252.054 us; speedup vs baseline: 4.7139x; 4.7139x over previous
//
#include <hip/hip_runtime.h>

// FDTD rollout, temporally blocked (TS=16 steps/launch), latency-reordered.
// 256 blocks x 512 threads; block = 32x32 output tile via 64x64 halo region.
// Thread = 8-row x 1-col register strip (lane = column, wave = 8-row band).
// LDS: only inter-wave boundary rows, double-buffered. Horizontal neighbors
// via DPP. Per-step reorder vs R7:
//   barrier -> issue ds_reads(upb,dnb) -> compute rows 1..6 (no LDS dep)
//   -> rows 0,7 (consume LDS) -> ds_write -> store PREVIOUS step's output
//   (sto[] double-buffer; store regs not reused for 2 steps) -> rotate
//   -> lgkm-only barrier. Global stores never on the critical path.

#define HH 512
#define WW 512
#define TILE 32
#define TS 16
#define NW 8      // waves per block
#define RPT 8     // rows per thread
#define PHC ((float)(2.0 * 3.1415926 * 100.0))

// LDS-only barrier: orders ds ops without draining vmcnt (stores in flight).
#define LDS_BARRIER() asm volatile("s_waitcnt lgkmcnt(0)\n\ts_barrier" ::: "memory")

#if __has_builtin(__builtin_amdgcn_update_dpp)
__device__ __forceinline__ float nbrL(float x) {   // value from lane-1 (left)
    int i = __builtin_bit_cast(int, x);
    i = __builtin_amdgcn_update_dpp(i, i, 0x138, 0xf, 0xf, false); // wave_shr:1
    return __builtin_bit_cast(float, i);
}
__device__ __forceinline__ float nbrR(float x) {   // value from lane+1 (right)
    int i = __builtin_bit_cast(int, x);
    i = __builtin_amdgcn_update_dpp(i, i, 0x130, 0xf, 0xf, false); // wave_shl:1
    return __builtin_bit_cast(float, i);
}
#else
__device__ __forceinline__ float nbrL(float x) { return __shfl_up(x, 1, 64); }
__device__ __forceinline__ float nbrR(float x) { return __shfl_down(x, 1, 64); }
#endif

__global__ __launch_bounds__(512)
void fdtd_reord(const float* __restrict__ prevF,
                const float* __restrict__ curF,
                const float* __restrict__ cmap,
                const int* __restrict__ locx,
                const int* __restrict__ locy,
                const int* __restrict__ pb,
                const int* __restrict__ pid2,
                float* __restrict__ out,
                int t0, int nk)
{
    __shared__ float sb[2][NW][2][64];   // [buf][wave][top/bottom row][col]

    const int lane = threadIdx.x & 63;
    const int w    = threadIdx.x >> 6;
    const int bx   = blockIdx.x & 15;
    const int by   = blockIdx.x >> 4;
    const int gx0  = bx * TILE - TS;
    const int gy0  = by * TILE - TS;
    const int gc   = gx0 + lane;
    const int R    = w * RPT;            // local row base

    const int lx0 = locx[0], ly0 = locy[0];
    const int lx1 = locx[1], ly1 = locy[1];
    const int lx2 = locx[2], ly2 = locy[2];
    const int Bn  = pb[0] * pid2[0];

    float cur[RPT], pv[RPT], rr[RPT], cv[RPT], sto[RPT];
    unsigned smask = 0, m0 = 0, m511 = 0;
    const bool colOK = (gc >= 0) & (gc < WW);

    #pragma unroll
    for (int j = 0; j < RPT; ++j) {
        const int gr = gy0 + R + j;
        float c = 0.f, ce = 0.f, pp = 0.f;
        if (colOK && gr >= 0 && gr < HH) {
            const int gi = gr * WW + gc;
            c  = cmap[gi];
            ce = curF[gi];
            pp = prevF[gi];
        }
        cur[j] = ce; pv[j] = pp; cv[j] = c;
        rr[j]  = 1.0e-8f * c * c;
        sto[j] = 0.f;
        if ((gr == lx0 && gc == ly0) || (gr == lx1 && gc == ly1) ||
            (gr == lx2 && gc == ly2)) smask |= (1u << j);
        if (gr == 0)      m0   |= (1u << j);
        if (gr == HH - 1) m511 |= (1u << j);
    }
    sb[0][w][0][lane] = cur[0];
    sb[0][w][1][lane] = cur[RPT - 1];
    __syncthreads();

    // clamped LDS slots for region-edge waves (garbage-safe halo)
    const int wup = (w == 0)      ? 0      : w - 1;
    const int sup = (w == 0)      ? 0      : 1;
    const int wdn = (w == NW - 1) ? NW - 1 : w + 1;
    const int sdn = (w == NW - 1) ? 1      : 0;

    const bool edge    = (bx == 0) | (bx == 15) | (by == 0) | (by == 15);
    const bool doStore = (w >= 2) & (w <= 5) & (lane >= 16) & (lane < 48);
    // running output pointer: sto (holding step k-1) is stored at step k
    // to plane t0+k-2; opc starts at plane t0 and advances HW per step.
    float* opc = out + (size_t)t0 * (size_t)(HH * WW)
                     + (size_t)(gy0 + R) * WW + gc;

    if (!edge) {
        // ----------------- interior blocks: branch-free stencil ------------
        #pragma unroll 4
        for (int k = 1; k <= nk; ++k) {
            const int p = (k - 1) & 1;
            // issue halo reads early; consumed only by rows 0 and 7
            const float upb = sb[p][wup][sup][lane];
            const float dnb = sb[p][wdn][sdn][lane];
            const float srcv =
                1500.0f * __sinf(PHC * (float)(Bn + t0 + k + 1) * 1.0e-4f);
            float nc[RPT];
            #pragma unroll
            for (int j = 1; j < RPT - 1; ++j) {      // interior rows first
                const float c = cur[j];
                const float l = nbrL(c);
                const float r = nbrR(c);
                float v = 2.f * c - pv[j] +
                          rr[j] * (((cur[j - 1] + cur[j + 1]) + (l + r)) - 4.f * c);
                nc[j] = ((smask >> j) & 1u) ? srcv : v;
            }
            {   // boundary rows last (LDS latency hidden under interior VALU)
                const float c0 = cur[0];
                float v0 = 2.f * c0 - pv[0] +
                           rr[0] * (((upb + cur[1]) + (nbrL(c0) + nbrR(c0))) - 4.f * c0);
                nc[0] = (smask & 1u) ? srcv : v0;
                const float c7 = cur[RPT - 1];
                float v7 = 2.f * c7 - pv[RPT - 1] +
                           rr[RPT - 1] * (((cur[RPT - 2] + dnb) +
                                           (nbrL(c7) + nbrR(c7))) - 4.f * c7);
                nc[RPT - 1] = ((smask >> (RPT - 1)) & 1u) ? srcv : v7;
            }
            sb[p ^ 1][w][0][lane] = nc[0];
            sb[p ^ 1][w][1][lane] = nc[RPT - 1];
            if (doStore) {
                if (k > 1) {                 // flush PREVIOUS step's output
                    #pragma unroll
                    for (int j = 0; j < RPT; ++j) opc[j * WW] = sto[j];
                    opc += (size_t)(HH * WW);
                }
                #pragma unroll
                for (int j = 0; j < RPT; ++j) sto[j] = nc[j];
            }
            #pragma unroll
            for (int j = 0; j < RPT; ++j) { pv[j] = cur[j]; cur[j] = nc[j]; }
            LDS_BARRIER();
        }
    } else {
        // ----------------- edge blocks: predicated boundary overrides ------
        const bool isC0   = (gc == 0);
        const bool isC511 = (gc == WW - 1);
        #pragma unroll 4
        for (int k = 1; k <= nk; ++k) {
            const int p = (k - 1) & 1;
            const float upb = sb[p][wup][sup][lane];
            const float dnb = sb[p][wdn][sdn][lane];
            const float srcv =
                1500.0f * __sinf(PHC * (float)(Bn + t0 + k + 1) * 1.0e-4f);
            float nc[RPT];
            #pragma unroll
            for (int j = 1; j < RPT - 1; ++j) {
                const float c = cur[j];
                const float u = cur[j - 1];
                const float d = cur[j + 1];
                const float l = nbrL(c);
                const float r = nbrR(c);
                float v = 2.f * c - pv[j] +
                          rr[j] * (((u + d) + (l + r)) - 4.f * c);
                v = ((smask >> j) & 1u) ? srcv : v;
                if ((m0 >> j) & 1u)   v = c - 1.0e-4f * cv[j] * (c - d);
                if (isC0)             v = c - 1.0e-4f * cv[j] * (c - r);
                if (isC511)           v = c - 1.0e-4f * cv[j] * (c - l);
                if ((m511 >> j) & 1u) v = c - 1.0e-4f * cv[j] * (c - u);
                nc[j] = v;
            }
            {
                const float c0 = cur[0];
                const float l0 = nbrL(c0), r0 = nbrR(c0);
                float v0 = 2.f * c0 - pv[0] +
                           rr[0] * (((upb + cur[1]) + (l0 + r0)) - 4.f * c0);
                v0 = (smask & 1u) ? srcv : v0;
                if (m0 & 1u)      v0 = c0 - 1.0e-4f * cv[0] * (c0 - cur[1]);
                if (isC0)         v0 = c0 - 1.0e-4f * cv[0] * (c0 - r0);
                if (isC511)       v0 = c0 - 1.0e-4f * cv[0] * (c0 - l0);
                if (m511 & 1u)    v0 = c0 - 1.0e-4f * cv[0] * (c0 - upb);
                nc[0] = v0;
                const int J = RPT - 1;
                const float c7 = cur[J];
                const float l7 = nbrL(c7), r7 = nbrR(c7);
                float v7 = 2.f * c7 - pv[J] +
                           rr[J] * (((cur[J - 1] + dnb) + (l7 + r7)) - 4.f * c7);
                v7 = ((smask >> J) & 1u) ? srcv : v7;
                if ((m0 >> J) & 1u)   v7 = c7 - 1.0e-4f * cv[J] * (c7 - dnb);
                if (isC0)             v7 = c7 - 1.0e-4f * cv[J] * (c7 - r7);
                if (isC511)           v7 = c7 - 1.0e-4f * cv[J] * (c7 - l7);
                if ((m511 >> J) & 1u) v7 = c7 - 1.0e-4f * cv[J] * (c7 - cur[J - 1]);
                nc[J] = v7;
            }
            sb[p ^ 1][w][0][lane] = nc[0];
            sb[p ^ 1][w][1][lane] = nc[RPT - 1];
            if (doStore) {
                if (k > 1) {
                    #pragma unroll
                    for (int j = 0; j < RPT; ++j) opc[j * WW] = sto[j];
                    opc += (size_t)(HH * WW);
                }
                #pragma unroll
                for (int j = 0; j < RPT; ++j) sto[j] = nc[j];
            }
            #pragma unroll
            for (int j = 0; j < RPT; ++j) { pv[j] = cur[j]; cur[j] = nc[j]; }
            LDS_BARRIER();
        }
    }
    // tail: flush the last step's output
    if (doStore) {
        #pragma unroll
        for (int j = 0; j < RPT; ++j) opc[j * WW] = sto[j];
    }
}

extern "C" void kernel_launch(void* const* d_in, const int* in_sizes, int n_in,
                              void* d_out, int out_size, void* d_ws, size_t ws_size,
                              hipStream_t stream) {
    const float* in_out = (const float*)d_in[0];   // [steps+2, 1, 512, 512]
    const float* cmap   = (const float*)d_in[1];   // [1,1,512,512]
    const int*   locx   = (const int*)d_in[2];
    const int*   locy   = (const int*)d_in[3];
    const int*   pb     = (const int*)d_in[4];     // bsize1
    const int*   pid2   = (const int*)d_in[5];     // id2
    float* out = (float*)d_out;

    const int HW = HH * WW;
    const int steps = out_size / HW;
    const int nblocks = (HH / TILE) * (WW / TILE); // 256

    for (int t0 = 0; t0 < steps; t0 += TS) {
        const int nk = (steps - t0 < TS) ? (steps - t0) : TS;
        const float *prevF, *curF;
        if (t0 == 0) {
            prevF = in_out;
            curF  = in_out + HW;
        } else {
            prevF = out + (size_t)(t0 - 2) * HW;
            curF  = out + (size_t)(t0 - 1) * HW;
        }
        hipLaunchKernelGGL(fdtd_reord, dim3(nblocks), dim3(512), 0, stream,
                           prevF, curF, cmap, locx, locy, pb, pid2, out, t0, nk);
    }
}

// Round 10
// 241.572 us; speedup vs baseline: 4.9184x; 1.0434x over previous
//
#include <hip/hip_runtime.h>

// FDTD rollout — SINGLE kernel (cooperative launch for co-residency), 256
// steps in 16 groups of TS=16, with NEIGHBOR-FLAG sync instead of grid sync.
// 256 blocks x 512 threads; block = 32x32 output tile via 64x64 halo region.
// Thread = 8-row x 1-col register strip (lane = column, wave = 8-row band).
// Inside a group: proven R7/R8 structure (DPP horizontal, register vertical,
// LDS only for inter-wave boundary rows, lgkm-only barrier per step).
// Between groups: drain own stores (vmcnt0 + syncthreads), publish
// flags[bid]=t0 (agent scope), spin on the 8 neighbors' flags, reload halo
// ring (agent-scope loads). All out-plane stores are agent-scope (sc1 ->
// LLC), so cross-XCD readers see them WITHOUT any L2 writeback/invalidate.
// Planes are written-once-read-once within the dispatch -> no stale lines.

#define HH 512
#define WW 512
#define TILE 32
#define TS 16
#define NW 8      // waves per block
#define RPT 8     // rows per thread
#define PHC ((float)(2.0 * 3.1415926 * 100.0))

// LDS-only barrier: orders ds ops without draining vmcnt (stores in flight).
#define LDS_BARRIER() asm volatile("s_waitcnt lgkmcnt(0)\n\ts_barrier" ::: "memory")

#if __has_builtin(__builtin_amdgcn_update_dpp)
__device__ __forceinline__ float nbrL(float x) {   // value from lane-1 (left)
    int i = __builtin_bit_cast(int, x);
    i = __builtin_amdgcn_update_dpp(i, i, 0x138, 0xf, 0xf, false); // wave_shr:1
    return __builtin_bit_cast(float, i);
}
__device__ __forceinline__ float nbrR(float x) {   // value from lane+1 (right)
    int i = __builtin_bit_cast(int, x);
    i = __builtin_amdgcn_update_dpp(i, i, 0x130, 0xf, 0xf, false); // wave_shl:1
    return __builtin_bit_cast(float, i);
}
#else
__device__ __forceinline__ float nbrL(float x) { return __shfl_up(x, 1, 64); }
__device__ __forceinline__ float nbrR(float x) { return __shfl_down(x, 1, 64); }
#endif

__global__ void fdtd_zero_flags(int* f) { f[threadIdx.x] = 0; }

__global__ __launch_bounds__(512)
void fdtd_flags_k(const float* __restrict__ in_out,
                  const float* __restrict__ cmap,
                  const int* __restrict__ locx,
                  const int* __restrict__ locy,
                  const int* __restrict__ pb,
                  const int* __restrict__ pid2,
                  float* __restrict__ out,
                  int steps, int* __restrict__ flags)
{
    __shared__ float sb[2][NW][2][64];   // [buf][wave][top/bottom row][col]

    const int tid  = threadIdx.x;
    const int lane = tid & 63;
    const int w    = tid >> 6;
    const int bx   = blockIdx.x & 15;
    const int by   = blockIdx.x >> 4;
    const int gx0  = bx * TILE - TS;
    const int gy0  = by * TILE - TS;
    const int gc   = gx0 + lane;
    const int R    = w * RPT;            // local row base

    const int lx0 = locx[0], ly0 = locy[0];
    const int lx1 = locx[1], ly1 = locy[1];
    const int lx2 = locx[2], ly2 = locy[2];
    const int Bn  = pb[0] * pid2[0];

    float cur[RPT], pv[RPT], rr[RPT], cv[RPT];
    bool  issrc[RPT];
    unsigned m0 = 0, m511 = 0;
    const bool colOK = (gc >= 0) & (gc < WW);

    // ---- one-time setup: c map, coefficients, masks, initial frames ----
    #pragma unroll
    for (int j = 0; j < RPT; ++j) {
        const int gr = gy0 + R + j;
        float c = 0.f, ce = 0.f, pp = 0.f;
        if (colOK && gr >= 0 && gr < HH) {
            const int gi = gr * WW + gc;
            c  = cmap[gi];
            ce = in_out[(size_t)(HH * WW) + gi];   // frame 1 (cur)
            pp = in_out[gi];                       // frame 0 (prev)
        }
        cur[j] = ce; pv[j] = pp; cv[j] = c;
        rr[j]  = 1.0e-8f * c * c;
        issrc[j] = (gr == lx0 && gc == ly0) || (gr == lx1 && gc == ly1) ||
                   (gr == lx2 && gc == ly2);
        if (gr == 0)      m0   |= (1u << j);
        if (gr == HH - 1) m511 |= (1u << j);
    }

    // clamped LDS slots for region-edge waves (garbage-safe halo)
    const int wup = (w == 0)      ? 0      : w - 1;
    const int sup = (w == 0)      ? 0      : 1;
    const int wdn = (w == NW - 1) ? NW - 1 : w + 1;
    const int sdn = (w == NW - 1) ? 1      : 0;

    const bool edge    = (bx == 0) | (bx == 15) | (by == 0) | (by == 15);
    const bool isC0    = (gc == 0);
    const bool isC511  = (gc == WW - 1);
    // center 32x32: these threads' cur/pv stay VALID across a whole group,
    // so they both store the output and keep their state between groups.
    const bool keep    = (w >= 2) & (w <= 5) & (lane >= 16) & (lane < 48);
    const size_t rowOff = (size_t)(gy0 + R) * WW + gc;

    for (int t0 = 0; t0 < steps; t0 += TS) {
        const int nk = (steps - t0 < TS) ? (steps - t0) : TS;

        if (t0 > 0) {
            // ---- group boundary: local (neighbor-only) synchronization ----
            asm volatile("s_waitcnt vmcnt(0)" ::: "memory"); // my stores @ LLC
            __syncthreads();                                 // all waves drained
            if (tid == 0)
                __hip_atomic_store(&flags[blockIdx.x], t0,
                                   __ATOMIC_RELAXED, __HIP_MEMORY_SCOPE_AGENT);
            if (tid < 8) {
                const int dy[8] = {-1,-1,-1, 0, 0, 1, 1, 1};
                const int dx[8] = {-1, 0, 1,-1, 1,-1, 0, 1};
                const int nby = by + dy[tid];
                const int nbx = bx + dx[tid];
                if (nby >= 0 && nby < 16 && nbx >= 0 && nbx < 16) {
                    const int nb = (nby << 4) | nbx;
                    while (__hip_atomic_load(&flags[nb], __ATOMIC_RELAXED,
                                             __HIP_MEMORY_SCOPE_AGENT) < t0)
                        __builtin_amdgcn_s_sleep(2);
                }
            }
            __syncthreads();                                 // neighbors ready
            if (!keep) {
                // reload halo ring of cur/pv (agent-scope: LLC-coherent)
                const float* cF = out + (size_t)(t0 - 1) * (size_t)(HH * WW);
                const float* pF = out + (size_t)(t0 - 2) * (size_t)(HH * WW);
                #pragma unroll
                for (int j = 0; j < RPT; ++j) {
                    const int gr = gy0 + R + j;
                    float ce = 0.f, pp = 0.f;
                    if (colOK && gr >= 0 && gr < HH) {
                        const int gi = gr * WW + gc;
                        ce = __hip_atomic_load(cF + gi, __ATOMIC_RELAXED,
                                               __HIP_MEMORY_SCOPE_AGENT);
                        pp = __hip_atomic_load(pF + gi, __ATOMIC_RELAXED,
                                               __HIP_MEMORY_SCOPE_AGENT);
                    }
                    cur[j] = ce; pv[j] = pp;
                }
            }
        }
        sb[0][w][0][lane] = cur[0];
        sb[0][w][1][lane] = cur[RPT - 1];
        __syncthreads();

        if (!edge) {
            // ------------- interior blocks: branch-free stencil ------------
            #pragma unroll 2
            for (int k = 1; k <= nk; ++k) {
                const int p = (k - 1) & 1;
                const float srcv =
                    1500.0f * __sinf(PHC * (float)(Bn + t0 + k + 1) * 1.0e-4f);
                const float upb = sb[p][wup][sup][lane];
                const float dnb = sb[p][wdn][sdn][lane];
                float nc[RPT];
                #pragma unroll
                for (int j = 0; j < RPT; ++j) {
                    const float c = cur[j];
                    const float u = (j == 0)       ? upb : cur[j - 1];
                    const float d = (j == RPT - 1) ? dnb : cur[j + 1];
                    const float l = nbrL(c);
                    const float r = nbrR(c);
                    float v = 2.f * c - pv[j] +
                              rr[j] * (((u + d) + (l + r)) - 4.f * c);
                    nc[j] = issrc[j] ? srcv : v;
                }
                sb[p ^ 1][w][0][lane] = nc[0];
                sb[p ^ 1][w][1][lane] = nc[RPT - 1];
                if (keep) {
                    float* op = out + (size_t)(t0 + k - 1) * (size_t)(HH * WW)
                                    + rowOff;
                    #pragma unroll
                    for (int j = 0; j < RPT; ++j)
                        __hip_atomic_store(op + j * WW, nc[j],
                                           __ATOMIC_RELAXED,
                                           __HIP_MEMORY_SCOPE_AGENT);
                }
                #pragma unroll
                for (int j = 0; j < RPT; ++j) { pv[j] = cur[j]; cur[j] = nc[j]; }
                LDS_BARRIER();
            }
        } else {
            // ------------- edge blocks: predicated boundary overrides ------
            #pragma unroll 2
            for (int k = 1; k <= nk; ++k) {
                const int p = (k - 1) & 1;
                const float srcv =
                    1500.0f * __sinf(PHC * (float)(Bn + t0 + k + 1) * 1.0e-4f);
                const float upb = sb[p][wup][sup][lane];
                const float dnb = sb[p][wdn][sdn][lane];
                float nc[RPT];
                #pragma unroll
                for (int j = 0; j < RPT; ++j) {
                    const float c = cur[j];
                    const float u = (j == 0)       ? upb : cur[j - 1];
                    const float d = (j == RPT - 1) ? dnb : cur[j + 1];
                    const float l = nbrL(c);
                    const float r = nbrR(c);
                    float v = 2.f * c - pv[j] +
                              rr[j] * (((u + d) + (l + r)) - 4.f * c);
                    v = issrc[j] ? srcv : v;
                    // precedence (last wins): row0 < col0 < col511 < row511
                    if ((m0 >> j) & 1u)   v = c - 1.0e-4f * cv[j] * (c - d);
                    if (isC0)             v = c - 1.0e-4f * cv[j] * (c - r);
                    if (isC511)           v = c - 1.0e-4f * cv[j] * (c - l);
                    if ((m511 >> j) & 1u) v = c - 1.0e-4f * cv[j] * (c - u);
                    nc[j] = v;
                }
                sb[p ^ 1][w][0][lane] = nc[0];
                sb[p ^ 1][w][1][lane] = nc[RPT - 1];
                if (keep) {
                    float* op = out + (size_t)(t0 + k - 1) * (size_t)(HH * WW)
                                    + rowOff;
                    #pragma unroll
                    for (int j = 0; j < RPT; ++j)
                        __hip_atomic_store(op + j * WW, nc[j],
                                           __ATOMIC_RELAXED,
                                           __HIP_MEMORY_SCOPE_AGENT);
                }
                #pragma unroll
                for (int j = 0; j < RPT; ++j) { pv[j] = cur[j]; cur[j] = nc[j]; }
                LDS_BARRIER();
            }
        }
    }
}

extern "C" void kernel_launch(void* const* d_in, const int* in_sizes, int n_in,
                              void* d_out, int out_size, void* d_ws, size_t ws_size,
                              hipStream_t stream) {
    const float* in_out = (const float*)d_in[0];   // [steps+2, 1, 512, 512]
    const float* cmap   = (const float*)d_in[1];   // [1,1,512,512]
    const int*   locx   = (const int*)d_in[2];
    const int*   locy   = (const int*)d_in[3];
    const int*   pb     = (const int*)d_in[4];     // bsize1
    const int*   pid2   = (const int*)d_in[5];     // id2
    float*       outp   = (float*)d_out;
    int*         flags  = (int*)d_ws;              // 256 progress flags

    const int HW = HH * WW;
    int steps = out_size / HW;

    hipLaunchKernelGGL(fdtd_zero_flags, dim3(1), dim3(256), 0, stream, flags);

    void* args[] = { (void*)&in_out, (void*)&cmap, (void*)&locx, (void*)&locy,
                     (void*)&pb, (void*)&pid2, (void*)&outp, (void*)&steps,
                     (void*)&flags };
    hipLaunchCooperativeKernel((const void*)fdtd_flags_k,
                               dim3((HH / TILE) * (WW / TILE)),  // 256 blocks
                               dim3(512), args, 0, stream);
}

// Round 11
// 241.543 us; speedup vs baseline: 4.9190x; 1.0001x over previous
//
#include <hip/hip_runtime.h>

// FDTD rollout — SINGLE kernel (cooperative launch for co-residency), 256
// steps in 16 groups of TS=16, NEIGHBOR-FLAG sync between groups.
// 256 blocks x 1024 threads; block = 32x32 output tile via 64x64 halo region.
// Thread = 4-row x 1-col register strip (lane = column, wave = 4-row band,
// 16 waves = 4 waves/SIMD for latency hiding -- the R10 post-mortem lever).
// Inside a group: DPP horizontal, register vertical, LDS only for inter-wave
// boundary rows, lgkm-only barrier per step. Between groups: drain stores,
// publish flags[bid], spin on 8 neighbor flags, reload halo ring (agent
// scope, LLC-coherent; planes are written-once-read-once in the dispatch).

#define HH 512
#define WW 512
#define TILE 32
#define TS 16
#define NW 16     // waves per block
#define RPT 4     // rows per thread
#define PHC ((float)(2.0 * 3.1415926 * 100.0))

// LDS-only barrier: orders ds ops without draining vmcnt (stores in flight).
#define LDS_BARRIER() asm volatile("s_waitcnt lgkmcnt(0)\n\ts_barrier" ::: "memory")

#if __has_builtin(__builtin_amdgcn_update_dpp)
__device__ __forceinline__ float nbrL(float x) {   // value from lane-1 (left)
    int i = __builtin_bit_cast(int, x);
    i = __builtin_amdgcn_update_dpp(i, i, 0x138, 0xf, 0xf, false); // wave_shr:1
    return __builtin_bit_cast(float, i);
}
__device__ __forceinline__ float nbrR(float x) {   // value from lane+1 (right)
    int i = __builtin_bit_cast(int, x);
    i = __builtin_amdgcn_update_dpp(i, i, 0x130, 0xf, 0xf, false); // wave_shl:1
    return __builtin_bit_cast(float, i);
}
#else
__device__ __forceinline__ float nbrL(float x) { return __shfl_up(x, 1, 64); }
__device__ __forceinline__ float nbrR(float x) { return __shfl_down(x, 1, 64); }
#endif

__global__ void fdtd_zero_flags(int* f) { f[threadIdx.x] = 0; }

__global__ __launch_bounds__(1024)
void fdtd_flags_k(const float* __restrict__ in_out,
                  const float* __restrict__ cmap,
                  const int* __restrict__ locx,
                  const int* __restrict__ locy,
                  const int* __restrict__ pb,
                  const int* __restrict__ pid2,
                  float* __restrict__ out,
                  int steps, int* __restrict__ flags)
{
    __shared__ float sb[2][NW][2][64];   // [buf][wave][top/bottom row][col]

    const int tid  = threadIdx.x;
    const int lane = tid & 63;
    const int w    = tid >> 6;           // 0..15
    const int bx   = blockIdx.x & 15;
    const int by   = blockIdx.x >> 4;
    const int gx0  = bx * TILE - TS;
    const int gy0  = by * TILE - TS;
    const int gc   = gx0 + lane;
    const int R    = w * RPT;            // local row base (0..60)

    const int lx0 = locx[0], ly0 = locy[0];
    const int lx1 = locx[1], ly1 = locy[1];
    const int lx2 = locx[2], ly2 = locy[2];
    const int Bn  = pb[0] * pid2[0];

    float cur[RPT], pv[RPT], rr[RPT], cv[RPT];
    bool  issrc[RPT];
    unsigned m0 = 0, m511 = 0;
    const bool colOK = (gc >= 0) & (gc < WW);

    // ---- one-time setup: c map, coefficients, masks, initial frames ----
    #pragma unroll
    for (int j = 0; j < RPT; ++j) {
        const int gr = gy0 + R + j;
        float c = 0.f, ce = 0.f, pp = 0.f;
        if (colOK && gr >= 0 && gr < HH) {
            const int gi = gr * WW + gc;
            c  = cmap[gi];
            ce = in_out[(size_t)(HH * WW) + gi];   // frame 1 (cur)
            pp = in_out[gi];                       // frame 0 (prev)
        }
        cur[j] = ce; pv[j] = pp; cv[j] = c;
        rr[j]  = 1.0e-8f * c * c;
        issrc[j] = (gr == lx0 && gc == ly0) || (gr == lx1 && gc == ly1) ||
                   (gr == lx2 && gc == ly2);
        if (gr == 0)      m0   |= (1u << j);
        if (gr == HH - 1) m511 |= (1u << j);
    }

    // clamped LDS slots for region-edge waves (garbage-safe halo)
    const int wup = (w == 0)      ? 0      : w - 1;
    const int sup = (w == 0)      ? 0      : 1;
    const int wdn = (w == NW - 1) ? NW - 1 : w + 1;
    const int sdn = (w == NW - 1) ? 1      : 0;

    const bool edge    = (bx == 0) | (bx == 15) | (by == 0) | (by == 15);
    const bool isC0    = (gc == 0);
    const bool isC511  = (gc == WW - 1);
    // center 32x32: waves 4..11 hold rows 16..47; their cur/pv stay valid
    // across a whole group -> they store output AND keep state.
    const bool keep    = (w >= 4) & (w <= 11) & (lane >= 16) & (lane < 48);
    const size_t rowOff = (size_t)(gy0 + R) * WW + gc;

    for (int t0 = 0; t0 < steps; t0 += TS) {
        const int nk = (steps - t0 < TS) ? (steps - t0) : TS;

        if (t0 > 0) {
            // ---- group boundary: local (neighbor-only) synchronization ----
            asm volatile("s_waitcnt vmcnt(0)" ::: "memory"); // my stores @ LLC
            __syncthreads();                                 // all waves drained
            if (tid == 0)
                __hip_atomic_store(&flags[blockIdx.x], t0,
                                   __ATOMIC_RELAXED, __HIP_MEMORY_SCOPE_AGENT);
            if (tid < 8) {
                const int dy[8] = {-1,-1,-1, 0, 0, 1, 1, 1};
                const int dx[8] = {-1, 0, 1,-1, 1,-1, 0, 1};
                const int nby = by + dy[tid];
                const int nbx = bx + dx[tid];
                if (nby >= 0 && nby < 16 && nbx >= 0 && nbx < 16) {
                    const int nb = (nby << 4) | nbx;
                    while (__hip_atomic_load(&flags[nb], __ATOMIC_RELAXED,
                                             __HIP_MEMORY_SCOPE_AGENT) < t0)
                        __builtin_amdgcn_s_sleep(2);
                }
            }
            __syncthreads();                                 // neighbors ready
            if (!keep) {
                // reload halo ring of cur/pv (agent-scope: LLC-coherent)
                const float* cF = out + (size_t)(t0 - 1) * (size_t)(HH * WW);
                const float* pF = out + (size_t)(t0 - 2) * (size_t)(HH * WW);
                #pragma unroll
                for (int j = 0; j < RPT; ++j) {
                    const int gr = gy0 + R + j;
                    float ce = 0.f, pp = 0.f;
                    if (colOK && gr >= 0 && gr < HH) {
                        const int gi = gr * WW + gc;
                        ce = __hip_atomic_load(cF + gi, __ATOMIC_RELAXED,
                                               __HIP_MEMORY_SCOPE_AGENT);
                        pp = __hip_atomic_load(pF + gi, __ATOMIC_RELAXED,
                                               __HIP_MEMORY_SCOPE_AGENT);
                    }
                    cur[j] = ce; pv[j] = pp;
                }
            }
        }
        sb[0][w][0][lane] = cur[0];
        sb[0][w][1][lane] = cur[RPT - 1];
        __syncthreads();

        if (!edge) {
            // ------------- interior blocks: branch-free stencil ------------
            #pragma unroll 2
            for (int k = 1; k <= nk; ++k) {
                const int p = (k - 1) & 1;
                const float srcv =
                    1500.0f * __sinf(PHC * (float)(Bn + t0 + k + 1) * 1.0e-4f);
                const float upb = sb[p][wup][sup][lane];
                const float dnb = sb[p][wdn][sdn][lane];
                float nc[RPT];
                #pragma unroll
                for (int j = 0; j < RPT; ++j) {
                    const float c = cur[j];
                    const float u = (j == 0)       ? upb : cur[j - 1];
                    const float d = (j == RPT - 1) ? dnb : cur[j + 1];
                    const float l = nbrL(c);
                    const float r = nbrR(c);
                    float v = 2.f * c - pv[j] +
                              rr[j] * (((u + d) + (l + r)) - 4.f * c);
                    nc[j] = issrc[j] ? srcv : v;
                }
                sb[p ^ 1][w][0][lane] = nc[0];
                sb[p ^ 1][w][1][lane] = nc[RPT - 1];
                if (keep) {
                    float* op = out + (size_t)(t0 + k - 1) * (size_t)(HH * WW)
                                    + rowOff;
                    #pragma unroll
                    for (int j = 0; j < RPT; ++j)
                        __hip_atomic_store(op + j * WW, nc[j],
                                           __ATOMIC_RELAXED,
                                           __HIP_MEMORY_SCOPE_AGENT);
                }
                #pragma unroll
                for (int j = 0; j < RPT; ++j) { pv[j] = cur[j]; cur[j] = nc[j]; }
                LDS_BARRIER();
            }
        } else {
            // ------------- edge blocks: predicated boundary overrides ------
            #pragma unroll 2
            for (int k = 1; k <= nk; ++k) {
                const int p = (k - 1) & 1;
                const float srcv =
                    1500.0f * __sinf(PHC * (float)(Bn + t0 + k + 1) * 1.0e-4f);
                const float upb = sb[p][wup][sup][lane];
                const float dnb = sb[p][wdn][sdn][lane];
                float nc[RPT];
                #pragma unroll
                for (int j = 0; j < RPT; ++j) {
                    const float c = cur[j];
                    const float u = (j == 0)       ? upb : cur[j - 1];
                    const float d = (j == RPT - 1) ? dnb : cur[j + 1];
                    const float l = nbrL(c);
                    const float r = nbrR(c);
                    float v = 2.f * c - pv[j] +
                              rr[j] * (((u + d) + (l + r)) - 4.f * c);
                    v = issrc[j] ? srcv : v;
                    // precedence (last wins): row0 < col0 < col511 < row511
                    if ((m0 >> j) & 1u)   v = c - 1.0e-4f * cv[j] * (c - d);
                    if (isC0)             v = c - 1.0e-4f * cv[j] * (c - r);
                    if (isC511)           v = c - 1.0e-4f * cv[j] * (c - l);
                    if ((m511 >> j) & 1u) v = c - 1.0e-4f * cv[j] * (c - u);
                    nc[j] = v;
                }
                sb[p ^ 1][w][0][lane] = nc[0];
                sb[p ^ 1][w][1][lane] = nc[RPT - 1];
                if (keep) {
                    float* op = out + (size_t)(t0 + k - 1) * (size_t)(HH * WW)
                                    + rowOff;
                    #pragma unroll
                    for (int j = 0; j < RPT; ++j)
                        __hip_atomic_store(op + j * WW, nc[j],
                                           __ATOMIC_RELAXED,
                                           __HIP_MEMORY_SCOPE_AGENT);
                }
                #pragma unroll
                for (int j = 0; j < RPT; ++j) { pv[j] = cur[j]; cur[j] = nc[j]; }
                LDS_BARRIER();
            }
        }
    }
}

extern "C" void kernel_launch(void* const* d_in, const int* in_sizes, int n_in,
                              void* d_out, int out_size, void* d_ws, size_t ws_size,
                              hipStream_t stream) {
    const float* in_out = (const float*)d_in[0];   // [steps+2, 1, 512, 512]
    const float* cmap   = (const float*)d_in[1];   // [1,1,512,512]
    const int*   locx   = (const int*)d_in[2];
    const int*   locy   = (const int*)d_in[3];
    const int*   pb     = (const int*)d_in[4];     // bsize1
    const int*   pid2   = (const int*)d_in[5];     // id2
    float*       outp   = (float*)d_out;
    int*         flags  = (int*)d_ws;              // 256 progress flags

    const int HW = HH * WW;
    int steps = out_size / HW;

    hipLaunchKernelGGL(fdtd_zero_flags, dim3(1), dim3(256), 0, stream, flags);

    void* args[] = { (void*)&in_out, (void*)&cmap, (void*)&locx, (void*)&locy,
                     (void*)&pb, (void*)&pid2, (void*)&outp, (void*)&steps,
                     (void*)&flags };
    hipLaunchCooperativeKernel((const void*)fdtd_flags_k,
                               dim3((HH / TILE) * (WW / TILE)),  // 256 blocks
                               dim3(1024), args, 0, stream);
}

// Round 12
// 236.809 us; speedup vs baseline: 5.0173x; 1.0200x over previous
//
#include <hip/hip_runtime.h>

// FDTD rollout — SINGLE kernel (cooperative launch), 256 steps in 16 groups
// of TS=16, neighbor-flag sync between groups (R10, proven). NEW: inside a
// group there is NO per-step block barrier. Waves exchange boundary rows
// through double-buffered LDS and synchronize pairwise via per-wave LDS
// step counters (release/acquire, workgroup scope). Skew <= 1 step between
// adjacent waves is safe with 2 buffers: executing step k requires
// cnt[w+-1] >= k-1, which also proves neighbors finished READING the buffer
// this step overwrites. Interior rows (no halo dep) are computed before the
// counter check so the spin + halo-read latency hides under VALU.

#define HH 512
#define WW 512
#define TILE 32
#define TS 16
#define NW 8      // waves per block
#define RPT 8     // rows per thread
#define PHC ((float)(2.0 * 3.1415926 * 100.0))

#if __has_builtin(__builtin_amdgcn_update_dpp)
__device__ __forceinline__ float nbrL(float x) {   // value from lane-1 (left)
    int i = __builtin_bit_cast(int, x);
    i = __builtin_amdgcn_update_dpp(i, i, 0x138, 0xf, 0xf, false); // wave_shr:1
    return __builtin_bit_cast(float, i);
}
__device__ __forceinline__ float nbrR(float x) {   // value from lane+1 (right)
    int i = __builtin_bit_cast(int, x);
    i = __builtin_amdgcn_update_dpp(i, i, 0x130, 0xf, 0xf, false); // wave_shl:1
    return __builtin_bit_cast(float, i);
}
#else
__device__ __forceinline__ float nbrL(float x) { return __shfl_up(x, 1, 64); }
__device__ __forceinline__ float nbrR(float x) { return __shfl_down(x, 1, 64); }
#endif

__global__ void fdtd_zero_flags(int* f) { f[threadIdx.x] = 0; }

__global__ __launch_bounds__(512)
void fdtd_dflow(const float* __restrict__ in_out,
                const float* __restrict__ cmap,
                const int* __restrict__ locx,
                const int* __restrict__ locy,
                const int* __restrict__ pb,
                const int* __restrict__ pid2,
                float* __restrict__ out,
                int steps, int* __restrict__ flags)
{
    __shared__ float sb[2][NW][2][64];   // [buf][wave][top/bottom row][col]
    __shared__ int   cnt[NW];            // per-wave completed-step counter

    const int tid  = threadIdx.x;
    const int lane = tid & 63;
    const int w    = tid >> 6;
    const int bx   = blockIdx.x & 15;
    const int by   = blockIdx.x >> 4;
    const int gx0  = bx * TILE - TS;
    const int gy0  = by * TILE - TS;
    const int gc   = gx0 + lane;
    const int R    = w * RPT;            // local row base

    const int lx0 = locx[0], ly0 = locy[0];
    const int lx1 = locx[1], ly1 = locy[1];
    const int lx2 = locx[2], ly2 = locy[2];
    const int Bn  = pb[0] * pid2[0];

    float cur[RPT], pv[RPT], rr[RPT], cv[RPT];
    bool  issrc[RPT];
    unsigned m0 = 0, m511 = 0;
    const bool colOK = (gc >= 0) & (gc < WW);

    // ---- one-time setup ----
    #pragma unroll
    for (int j = 0; j < RPT; ++j) {
        const int gr = gy0 + R + j;
        float c = 0.f, ce = 0.f, pp = 0.f;
        if (colOK && gr >= 0 && gr < HH) {
            const int gi = gr * WW + gc;
            c  = cmap[gi];
            ce = in_out[(size_t)(HH * WW) + gi];   // frame 1 (cur)
            pp = in_out[gi];                       // frame 0 (prev)
        }
        cur[j] = ce; pv[j] = pp; cv[j] = c;
        rr[j]  = 1.0e-8f * c * c;
        issrc[j] = (gr == lx0 && gc == ly0) || (gr == lx1 && gc == ly1) ||
                   (gr == lx2 && gc == ly2);
        if (gr == 0)      m0   |= (1u << j);
        if (gr == HH - 1) m511 |= (1u << j);
    }
    if (tid < NW) cnt[tid] = 0;

    const int wup = (w == 0)      ? 0      : w - 1;
    const int sup = (w == 0)      ? 0      : 1;
    const int wdn = (w == NW - 1) ? NW - 1 : w + 1;
    const int sdn = (w == NW - 1) ? 1      : 0;

    const bool edge    = (bx == 0) | (bx == 15) | (by == 0) | (by == 15);
    const bool isC0    = (gc == 0);
    const bool isC511  = (gc == WW - 1);
    const bool keep    = (w >= 2) & (w <= 5) & (lane >= 16) & (lane < 48);
    const size_t rowOff = (size_t)(gy0 + R) * WW + gc;

    for (int t0 = 0; t0 < steps; t0 += TS) {
        const int nk = (steps - t0 < TS) ? (steps - t0) : TS;

        if (t0 > 0) {
            // ---- group boundary: inter-block neighbor-flag sync (R10) ----
            asm volatile("s_waitcnt vmcnt(0)" ::: "memory");
            __syncthreads();
            if (tid == 0)
                __hip_atomic_store(&flags[blockIdx.x], t0,
                                   __ATOMIC_RELAXED, __HIP_MEMORY_SCOPE_AGENT);
            if (tid < 8) {
                const int dy[8] = {-1,-1,-1, 0, 0, 1, 1, 1};
                const int dx[8] = {-1, 0, 1,-1, 1,-1, 0, 1};
                const int nby = by + dy[tid];
                const int nbx = bx + dx[tid];
                if (nby >= 0 && nby < 16 && nbx >= 0 && nbx < 16) {
                    const int nb = (nby << 4) | nbx;
                    while (__hip_atomic_load(&flags[nb], __ATOMIC_RELAXED,
                                             __HIP_MEMORY_SCOPE_AGENT) < t0)
                        __builtin_amdgcn_s_sleep(2);
                }
            }
            __syncthreads();
            if (!keep) {
                const float* cF = out + (size_t)(t0 - 1) * (size_t)(HH * WW);
                const float* pF = out + (size_t)(t0 - 2) * (size_t)(HH * WW);
                #pragma unroll
                for (int j = 0; j < RPT; ++j) {
                    const int gr = gy0 + R + j;
                    float ce = 0.f, pp = 0.f;
                    if (colOK && gr >= 0 && gr < HH) {
                        const int gi = gr * WW + gc;
                        ce = __hip_atomic_load(cF + gi, __ATOMIC_RELAXED,
                                               __HIP_MEMORY_SCOPE_AGENT);
                        pp = __hip_atomic_load(pF + gi, __ATOMIC_RELAXED,
                                               __HIP_MEMORY_SCOPE_AGENT);
                    }
                    cur[j] = ce; pv[j] = pp;
                }
            }
        }
        sb[0][w][0][lane] = cur[0];
        sb[0][w][1][lane] = cur[RPT - 1];
        __syncthreads();   // also publishes cnt init / group convergence

        if (!edge) {
            // --------- interior blocks: barrier-free skewed dataflow -------
            #pragma unroll 2
            for (int k = 1; k <= nk; ++k) {
                const int p = (k - 1) & 1;
                const float srcv =
                    1500.0f * __sinf(PHC * (float)(Bn + t0 + k + 1) * 1.0e-4f);
                float nc[RPT];
                // interior rows first (no halo dependence)
                #pragma unroll
                for (int j = 1; j < RPT - 1; ++j) {
                    const float c = cur[j];
                    const float l = nbrL(c);
                    const float r = nbrR(c);
                    float v = 2.f * c - pv[j] +
                              rr[j] * (((cur[j - 1] + cur[j + 1]) + (l + r)) - 4.f * c);
                    nc[j] = ((issrc[j])) ? srcv : v;
                }
                // wave-to-wave sync: neighbors must have finished step k-1
                const int need = t0 + k - 1;
                while (__hip_atomic_load(&cnt[wup], __ATOMIC_ACQUIRE,
                                         __HIP_MEMORY_SCOPE_WORKGROUP) < need)
                    __builtin_amdgcn_s_sleep(1);
                while (__hip_atomic_load(&cnt[wdn], __ATOMIC_ACQUIRE,
                                         __HIP_MEMORY_SCOPE_WORKGROUP) < need)
                    __builtin_amdgcn_s_sleep(1);
                const float upb = sb[p][wup][sup][lane];
                const float dnb = sb[p][wdn][sdn][lane];
                {
                    const float c0 = cur[0];
                    float v0 = 2.f * c0 - pv[0] +
                               rr[0] * (((upb + cur[1]) + (nbrL(c0) + nbrR(c0))) - 4.f * c0);
                    nc[0] = issrc[0] ? srcv : v0;
                    const int J = RPT - 1;
                    const float c7 = cur[J];
                    float v7 = 2.f * c7 - pv[J] +
                               rr[J] * (((cur[J - 1] + dnb) + (nbrL(c7) + nbrR(c7))) - 4.f * c7);
                    nc[J] = issrc[J] ? srcv : v7;
                }
                sb[p ^ 1][w][0][lane] = nc[0];
                sb[p ^ 1][w][1][lane] = nc[RPT - 1];
                __hip_atomic_store(&cnt[w], t0 + k, __ATOMIC_RELEASE,
                                   __HIP_MEMORY_SCOPE_WORKGROUP);
                if (keep) {
                    float* op = out + (size_t)(t0 + k - 1) * (size_t)(HH * WW)
                                    + rowOff;
                    #pragma unroll
                    for (int j = 0; j < RPT; ++j)
                        __hip_atomic_store(op + j * WW, nc[j],
                                           __ATOMIC_RELAXED,
                                           __HIP_MEMORY_SCOPE_AGENT);
                }
                #pragma unroll
                for (int j = 0; j < RPT; ++j) { pv[j] = cur[j]; cur[j] = nc[j]; }
            }
        } else {
            // --------- edge blocks: same protocol + boundary overrides -----
            #pragma unroll 2
            for (int k = 1; k <= nk; ++k) {
                const int p = (k - 1) & 1;
                const float srcv =
                    1500.0f * __sinf(PHC * (float)(Bn + t0 + k + 1) * 1.0e-4f);
                float nc[RPT];
                #pragma unroll
                for (int j = 1; j < RPT - 1; ++j) {
                    const float c = cur[j];
                    const float u = cur[j - 1];
                    const float d = cur[j + 1];
                    const float l = nbrL(c);
                    const float r = nbrR(c);
                    float v = 2.f * c - pv[j] +
                              rr[j] * (((u + d) + (l + r)) - 4.f * c);
                    v = issrc[j] ? srcv : v;
                    if ((m0 >> j) & 1u)   v = c - 1.0e-4f * cv[j] * (c - d);
                    if (isC0)             v = c - 1.0e-4f * cv[j] * (c - r);
                    if (isC511)           v = c - 1.0e-4f * cv[j] * (c - l);
                    if ((m511 >> j) & 1u) v = c - 1.0e-4f * cv[j] * (c - u);
                    nc[j] = v;
                }
                const int need = t0 + k - 1;
                while (__hip_atomic_load(&cnt[wup], __ATOMIC_ACQUIRE,
                                         __HIP_MEMORY_SCOPE_WORKGROUP) < need)
                    __builtin_amdgcn_s_sleep(1);
                while (__hip_atomic_load(&cnt[wdn], __ATOMIC_ACQUIRE,
                                         __HIP_MEMORY_SCOPE_WORKGROUP) < need)
                    __builtin_amdgcn_s_sleep(1);
                const float upb = sb[p][wup][sup][lane];
                const float dnb = sb[p][wdn][sdn][lane];
                {
                    const float c0 = cur[0];
                    const float l0 = nbrL(c0), r0 = nbrR(c0);
                    float v0 = 2.f * c0 - pv[0] +
                               rr[0] * (((upb + cur[1]) + (l0 + r0)) - 4.f * c0);
                    v0 = issrc[0] ? srcv : v0;
                    if (m0 & 1u)      v0 = c0 - 1.0e-4f * cv[0] * (c0 - cur[1]);
                    if (isC0)         v0 = c0 - 1.0e-4f * cv[0] * (c0 - r0);
                    if (isC511)       v0 = c0 - 1.0e-4f * cv[0] * (c0 - l0);
                    if (m511 & 1u)    v0 = c0 - 1.0e-4f * cv[0] * (c0 - upb);
                    nc[0] = v0;
                    const int J = RPT - 1;
                    const float c7 = cur[J];
                    const float l7 = nbrL(c7), r7 = nbrR(c7);
                    float v7 = 2.f * c7 - pv[J] +
                               rr[J] * (((cur[J - 1] + dnb) + (l7 + r7)) - 4.f * c7);
                    v7 = ((issrc[J])) ? srcv : v7;
                    if ((m0 >> J) & 1u)   v7 = c7 - 1.0e-4f * cv[J] * (c7 - dnb);
                    if (isC0)             v7 = c7 - 1.0e-4f * cv[J] * (c7 - r7);
                    if (isC511)           v7 = c7 - 1.0e-4f * cv[J] * (c7 - l7);
                    if ((m511 >> J) & 1u) v7 = c7 - 1.0e-4f * cv[J] * (c7 - cur[J - 1]);
                    nc[J] = v7;
                }
                sb[p ^ 1][w][0][lane] = nc[0];
                sb[p ^ 1][w][1][lane] = nc[RPT - 1];
                __hip_atomic_store(&cnt[w], t0 + k, __ATOMIC_RELEASE,
                                   __HIP_MEMORY_SCOPE_WORKGROUP);
                if (keep) {
                    float* op = out + (size_t)(t0 + k - 1) * (size_t)(HH * WW)
                                    + rowOff;
                    #pragma unroll
                    for (int j = 0; j < RPT; ++j)
                        __hip_atomic_store(op + j * WW, nc[j],
                                           __ATOMIC_RELAXED,
                                           __HIP_MEMORY_SCOPE_AGENT);
                }
                #pragma unroll
                for (int j = 0; j < RPT; ++j) { pv[j] = cur[j]; cur[j] = nc[j]; }
            }
        }
    }
}

extern "C" void kernel_launch(void* const* d_in, const int* in_sizes, int n_in,
                              void* d_out, int out_size, void* d_ws, size_t ws_size,
                              hipStream_t stream) {
    const float* in_out = (const float*)d_in[0];   // [steps+2, 1, 512, 512]
    const float* cmap   = (const float*)d_in[1];   // [1,1,512,512]
    const int*   locx   = (const int*)d_in[2];
    const int*   locy   = (const int*)d_in[3];
    const int*   pb     = (const int*)d_in[4];     // bsize1
    const int*   pid2   = (const int*)d_in[5];     // id2
    float*       outp   = (float*)d_out;
    int*         flags  = (int*)d_ws;              // 256 progress flags

    const int HW = HH * WW;
    int steps = out_size / HW;

    hipLaunchKernelGGL(fdtd_zero_flags, dim3(1), dim3(256), 0, stream, flags);

    void* args[] = { (void*)&in_out, (void*)&cmap, (void*)&locx, (void*)&locy,
                     (void*)&pb, (void*)&pid2, (void*)&outp, (void*)&steps,
                     (void*)&flags };
    hipLaunchCooperativeKernel((const void*)fdtd_dflow,
                               dim3((HH / TILE) * (WW / TILE)),  // 256 blocks
                               dim3(512), args, 0, stream);
}